// Round 12
// baseline (149.127 us; speedup 1.0000x reference)
//
#include <hip/hip_runtime.h>

// Problem: CausalSelfAttention  B=2 T=2048 C=1024 H=16 D=64, fp32 in/out.
// Pipeline: prep(cvt+tconv+tconv fused) -> GEMM1(128^2 bf16) -> rope+vtrans(fused)
//           -> attn8 (q-block-64, kv-split-4, single-read LDS tiles) -> GEMM2.

#define B_  2
#define T_  2048
#define C_  1024
#define H_  16
#define D_  64
#define N3_ 3072

typedef unsigned short ushortx8 __attribute__((ext_vector_type(8)));
typedef unsigned short ushortx4 __attribute__((ext_vector_type(4)));
typedef short bf16x8 __attribute__((ext_vector_type(8)));
typedef float f32x4 __attribute__((ext_vector_type(4)));
typedef float f32x16 __attribute__((ext_vector_type(16)));
typedef unsigned int uintx2 __attribute__((ext_vector_type(2)));

__device__ __forceinline__ unsigned short f2bf(float f) {
  union { float f; unsigned u; } v; v.f = f;
  unsigned r = v.u + 0x7FFFu + ((v.u >> 16) & 1u);   // RNE
  return (unsigned short)(r >> 16);
}
__device__ __forceinline__ float bf2f(unsigned short h) {
  union { unsigned u; float f; } v; v.u = ((unsigned)h) << 16;
  return v.f;
}
// pack two f32 -> 2xbf16 in one u32 (no builtin exists; m240)
__device__ __forceinline__ unsigned cvtpk_bf16(float lo, float hi) {
  unsigned r; asm("v_cvt_pk_bf16_f32 %0, %1, %2" : "=v"(r) : "v"(lo), "v"(hi));
  return r;
}
// async global->LDS, 16B per lane; dst must be wave-uniform (HW adds lane*16)
__device__ __forceinline__ void gload_lds16(const void* g, void* l) {
  __builtin_amdgcn_global_load_lds((const __attribute__((address_space(1))) void*)g,
                                   (__attribute__((address_space(3))) void*)l,
                                   16, 0, 0);
}

// ---- fused prep: blocks [0,4096) cvt x->bf16; [4096,7168) tconv Wqkv; [7168,8192) tconv Wout
__global__ __launch_bounds__(256) void prep_kernel(const float* __restrict__ x,
                                                   unsigned short* __restrict__ Xb,
                                                   const float* __restrict__ Wqkv,
                                                   unsigned short* __restrict__ WqkvT,
                                                   const float* __restrict__ Wout,
                                                   unsigned short* __restrict__ WoutT) {
  __shared__ float tile[32][33];
  const int bid = blockIdx.x;
  if (bid < 4096) {
    size_t i = ((size_t)bid * 256 + threadIdx.x) * 4;
    const float4 v = *(const float4*)(x + i);
    ushortx4 o;
    o[0] = f2bf(v.x); o[1] = f2bf(v.y); o[2] = f2bf(v.z); o[3] = f2bf(v.w);
    *(ushortx4*)(Xb + i) = o;
    return;
  }
  const float* W;
  unsigned short* WT;
  int K, N, n0, k0;
  if (bid < 7168) {
    const int idx = bid - 4096;
    W = Wqkv; WT = WqkvT; K = C_; N = N3_;
    n0 = (idx % (N3_ / 32)) * 32; k0 = (idx / (N3_ / 32)) * 32;
  } else {
    const int idx = bid - 7168;
    W = Wout; WT = WoutT; K = C_; N = C_;
    n0 = (idx % (C_ / 32)) * 32; k0 = (idx / (C_ / 32)) * 32;
  }
  const int tx = threadIdx.x & 31, ty = threadIdx.x >> 5;
#pragma unroll
  for (int i = 0; i < 4; ++i)
    tile[ty + i * 8][tx] = W[(size_t)(k0 + ty + i * 8) * N + n0 + tx];
  __syncthreads();
#pragma unroll
  for (int i = 0; i < 4; ++i)
    WT[(size_t)(n0 + ty + i * 8) * K + k0 + tx] = f2bf(tile[tx][ty + i * 8]);
}

// ---------------- GEMM: C[M][N] = A[M][K] * BT[N][K]^T (bf16 MFMA) ----------------
// 128x128 tile, BK=64, 4 waves (each 64x64), global_load_lds w/ XOR-swizzled source.
template <int OUTF32>
__global__ __launch_bounds__(256) void gemm_bt_kernel(const unsigned short* __restrict__ A,
                                                      const unsigned short* __restrict__ BT,
                                                      void* __restrict__ Cptr,
                                                      int M, int N, int K) {
  __shared__ unsigned short Alds[128 * 64];
  __shared__ unsigned short Blds[128 * 64];
  const int tid = threadIdx.x;
  const int w = tid >> 6, l = tid & 63;
  const int wr = w >> 1, wc = w & 1;
  const int lg = l >> 4, lr = l & 15;
  const int m0 = blockIdx.y * 128, n0 = blockIdx.x * 128;
  const int lr8 = l >> 3;                 // row within 8-row chunk
  const int lc8 = (l & 7) ^ lr8;          // pre-swizzled source col16 (T2 st-style)

  f32x4 acc[4][4];
#pragma unroll
  for (int i = 0; i < 4; ++i)
#pragma unroll
    for (int j = 0; j < 4; ++j) acc[i][j] = f32x4{0.f, 0.f, 0.f, 0.f};

  for (int k0 = 0; k0 < K; k0 += 64) {
    __syncthreads();
#pragma unroll
    for (int i = 0; i < 4; ++i) {
      const int ch = w * 4 + i;           // 16 chunks of 1024B per tile
      gload_lds16(A + (size_t)(m0 + ch * 8 + lr8) * K + k0 + lc8 * 8, &Alds[ch * 512]);
      gload_lds16(BT + (size_t)(n0 + ch * 8 + lr8) * K + k0 + lc8 * 8, &Blds[ch * 512]);
    }
    __syncthreads();
#pragma unroll
    for (int kc = 0; kc < 2; ++kc) {
      bf16x8 af[4], bfr[4];
#pragma unroll
      for (int mi = 0; mi < 4; ++mi) {
        const int row = wr * 64 + mi * 16 + lr;
        const int c16 = (kc * 4 + lg) ^ (row & 7);
        af[mi] = *(const bf16x8*)(&Alds[row * 64 + c16 * 8]);
      }
#pragma unroll
      for (int nj = 0; nj < 4; ++nj) {
        const int row = wc * 64 + nj * 16 + lr;
        const int c16 = (kc * 4 + lg) ^ (row & 7);
        bfr[nj] = *(const bf16x8*)(&Blds[row * 64 + c16 * 8]);
      }
#pragma unroll
      for (int mi = 0; mi < 4; ++mi)
#pragma unroll
        for (int nj = 0; nj < 4; ++nj)
          acc[mi][nj] = __builtin_amdgcn_mfma_f32_16x16x32_bf16(af[mi], bfr[nj], acc[mi][nj], 0, 0, 0);
    }
  }
#pragma unroll
  for (int mi = 0; mi < 4; ++mi)
#pragma unroll
    for (int nj = 0; nj < 4; ++nj)
#pragma unroll
      for (int j = 0; j < 4; ++j) {
        const int row = m0 + wr * 64 + mi * 16 + lg * 4 + j;  // C/D: row=(lane>>4)*4+j
        const int col = n0 + wc * 64 + nj * 16 + lr;          //      col=lane&15
        if (OUTF32) ((float*)Cptr)[(size_t)row * N + col] = acc[mi][nj][j];
        else ((unsigned short*)Cptr)[(size_t)row * N + col] = f2bf(acc[mi][nj][j]);
      }
}

// ---- fused RoPE-pack (z=0) + V-transpose (z=1) ----
__global__ __launch_bounds__(256) void rope_vtrans_kernel(const unsigned short* __restrict__ QKV,
                                                          unsigned short* __restrict__ Qp,
                                                          unsigned short* __restrict__ Kp,
                                                          unsigned short* __restrict__ Vt) {
  __shared__ unsigned short tile[64][72];
  const int tt = blockIdx.x, bh = blockIdx.y;
  const int b = bh >> 4, h = bh & 15;
  const int tid = threadIdx.x;
  if (blockIdx.z == 0) {
    const int half = tid >> 7;           // 0=q, 1=k
    const int r = (tid >> 1) & 63;
    const int d0 = (tid & 1) * 16;
    const int t = tt * 64 + r;
    const unsigned short* src = QKV + (size_t)(b * T_ + t) * N3_ + half * C_ + h * D_;
    ushortx8 lo0 = *(const ushortx8*)(src + d0);
    ushortx8 lo1 = *(const ushortx8*)(src + d0 + 8);
    ushortx8 hi0 = *(const ushortx8*)(src + d0 + 32);
    ushortx8 hi1 = *(const ushortx8*)(src + d0 + 40);
    ushortx8 olo0, olo1, ohi0, ohi1;
    const float scale = half ? 1.0f : 0.18033688011112042f;
    const float tf = (float)t;
#pragma unroll
    for (int jj = 0; jj < 16; ++jj) {
      const int d = d0 + jj;
      const float invf = exp2f((float)d * -0.41524101186092036f);
      const float ang = tf * invf;
      const float c = cosf(ang), s = sinf(ang);
      const float xl = bf2f(jj < 8 ? lo0[jj] : lo1[jj - 8]);
      const float xh = bf2f(jj < 8 ? hi0[jj] : hi1[jj - 8]);
      const unsigned short rl = f2bf((xl * c - xh * s) * scale);
      const unsigned short rh = f2bf((xh * c + xl * s) * scale);
      if (jj < 8) { olo0[jj] = rl; ohi0[jj] = rh; }
      else        { olo1[jj - 8] = rl; ohi1[jj - 8] = rh; }
    }
    unsigned short* dst = (half ? Kp : Qp) + ((size_t)bh * T_ + t) * D_;
    *(ushortx8*)(dst + d0) = olo0;
    *(ushortx8*)(dst + d0 + 8) = olo1;
    *(ushortx8*)(dst + d0 + 32) = ohi0;
    *(ushortx8*)(dst + d0 + 40) = ohi1;
  } else {
    {
      const int r = tid >> 2, seg = tid & 3;
      const unsigned short* src = QKV + (size_t)(b * T_ + tt * 64 + r) * N3_ + 2 * C_ + h * D_ + seg * 16;
      *(ushortx8*)(&tile[r][seg * 16]) = *(const ushortx8*)(src);
      *(ushortx8*)(&tile[r][seg * 16 + 8]) = *(const ushortx8*)(src + 8);
    }
    __syncthreads();
    {
      const int d = tid >> 2, ts = tid & 3;
      ushortx8 o0, o1;
#pragma unroll
      for (int i = 0; i < 8; ++i) { o0[i] = tile[ts * 16 + i][d]; o1[i] = tile[ts * 16 + 8 + i][d]; }
      unsigned short* dst = Vt + ((size_t)bh * D_ + d) * T_ + tt * 64 + ts * 16;
      *(ushortx8*)(dst) = o0;
      *(ushortx8*)(dst + 8) = o1;
    }
  }
}

// -------- causal flash attention v8: q-block-64, kv-split-4, single-read LDS --------
// Block = 64 q-rows (q-block g, head bh). 4 waves round-robin the kv tiles
// (wave w computes kt%4==w) so each staged tile is ds_read exactly ONCE.
// Each wave keeps private online-softmax state for both 32-row halves
// (swapped-operand 32x32x16; K/V frags read once, used for both halves).
// Staging = attn7's 3-buf counted-vmcnt; merge = attn5's 4-way LDS merge x2.
__global__ __launch_bounds__(256, 2) void attn8_kernel(const unsigned short* __restrict__ Qp,
                                                       const unsigned short* __restrict__ Kp,
                                                       const unsigned short* __restrict__ Vt,
                                                       unsigned short* __restrict__ Ob) {
  __shared__ unsigned short shm[24576];      // 48KB: K bufs [0,12288), V bufs [12288,24576)
  __shared__ float mstat[2][2][4][32];       // [strip][m/l][wave][q]
  const int tid = threadIdx.x, w = tid >> 6, l = tid & 63;
  const int lq = l & 31, hi = l >> 5;
  const int swz = lq & 7;
  const int bid = blockIdx.x;
  const int bh = bid & 31;                   // same head -> same XCD (bid%8)
  const int j = bid >> 5;                    // 0..31
  const int r = j & 7, q2 = j >> 3;
  // per-CU g-sets {31-r,16+r,15-r,r} sum to 62 (uniform); longest dispatched first
  const int g = (q2 == 0) ? (31 - r) : (q2 == 1) ? (16 + r) : (q2 == 2) ? (15 - r) : r;
  const int q0 = g * 64;
  const int ntiles = g + 1;
  const size_t koff = (size_t)bh * T_ * D_;
  const unsigned short* Kb = Kp + koff;
  const unsigned short* Vb = Vt + (size_t)bh * D_ * T_;
  const int lr8 = l >> 3, lc8 = (l & 7) ^ lr8;   // staging swizzle (as attn7)

  // Q frags, both 32-row halves: lane holds Q[q0(+32)+lq][ds*16+hi*8+..]
  bf16x8 qlo[4], qhi[4];
  {
    const unsigned short* qp = Qp + koff + (size_t)(q0 + lq) * D_ + hi * 8;
#pragma unroll
    for (int ds = 0; ds < 4; ++ds) {
      qlo[ds] = *(const bf16x8*)(qp + ds * 16);
      qhi[ds] = *(const bf16x8*)(qp + 32 * D_ + ds * 16);
    }
  }
  f32x16 oA0, oA1, oB0, oB1;
#pragma unroll
  for (int i = 0; i < 16; ++i) { oA0[i] = 0.f; oA1[i] = 0.f; oB0[i] = 0.f; oB1[i] = 0.f; }
  float mA = -3.0e38f, lA = 0.f, mB = -3.0e38f, lB = 0.f;

  // prologue: stage tile 0 into buf 0 (wave w stages chunks 2w,2w+1 of K and V)
#pragma unroll
  for (int i = 0; i < 2; ++i) {
    const int c = w * 2 + i;
    gload_lds16(Kb + (size_t)(c * 8 + lr8) * D_ + lc8 * 8, &shm[c * 512]);
    gload_lds16(Vb + (size_t)(c * 8 + lr8) * T_ + lc8 * 8, &shm[12288 + c * 512]);
  }

  for (int kt = 0; kt < ntiles; ++kt) {
    const int cur = kt % 3, nxt = (kt + 1) % 3;
    const int ktn = (kt + 1 < ntiles) ? kt + 1 : kt;
    const int kvn = ktn * 64;
#pragma unroll
    for (int i = 0; i < 2; ++i) {
      const int c = w * 2 + i;
      gload_lds16(Kb + (size_t)(kvn + c * 8 + lr8) * D_ + lc8 * 8, &shm[nxt * 4096 + c * 512]);
      gload_lds16(Vb + (size_t)(c * 8 + lr8) * T_ + kvn + lc8 * 8, &shm[12288 + nxt * 4096 + c * 512]);
    }
    asm volatile("s_waitcnt vmcnt(4)" ::: "memory");   // tile kt landed; kt+1 in flight
    __builtin_amdgcn_s_barrier();
    __builtin_amdgcn_sched_barrier(0);

    if ((kt & 3) == w) {      // this wave owns tile kt
      const unsigned short* KL = &shm[cur * 4096];
      const unsigned short* VL = &shm[12288 + cur * 4096];
      // S^T = K.Q^T for both q-halves; K frags read once, used twice
      f32x16 aL0, aL1, aH0, aH1;
#pragma unroll
      for (int i = 0; i < 16; ++i) { aL0[i] = 0.f; aL1[i] = 0.f; aH0[i] = 0.f; aH1[i] = 0.f; }
      __builtin_amdgcn_s_setprio(1);
#pragma unroll
      for (int ds = 0; ds < 4; ++ds) {
        const int slot = ((ds * 2 + hi) ^ swz) * 8;
        const bf16x8 kf0 = *(const bf16x8*)(&KL[lq * 64 + slot]);
        const bf16x8 kf1 = *(const bf16x8*)(&KL[(32 + lq) * 64 + slot]);
        aL0 = __builtin_amdgcn_mfma_f32_32x32x16_bf16(kf0, qlo[ds], aL0, 0, 0, 0);
        aL1 = __builtin_amdgcn_mfma_f32_32x32x16_bf16(kf1, qlo[ds], aL1, 0, 0, 0);
        aH0 = __builtin_amdgcn_mfma_f32_32x32x16_bf16(kf0, qhi[ds], aH0, 0, 0, 0);
        aH1 = __builtin_amdgcn_mfma_f32_32x32x16_bf16(kf1, qhi[ds], aH1, 0, 0, 0);
      }
      __builtin_amdgcn_s_setprio(0);
      if (kt == g) {   // diagonal tile: lo-q sees kv group0 masked, group1 none;
                       // hi-q sees group0 fully, group1 masked
#pragma unroll
        for (int rr = 0; rr < 16; ++rr) {
          const int kvloc = (rr & 3) + 8 * (rr >> 2) + 4 * hi;
          if (kvloc > lq) { aL0[rr] = -3.0e38f; aH1[rr] = -3.0e38f; }
          aL1[rr] = -3.0e38f;
        }
      }
      // ---- softmax lo-half ----
      float p0[16], p1[16];
      bf16x8 pfL0, pfL1, pfL2, pfL3, pfH0, pfH1, pfH2, pfH3;
      {
        float mx[8];
#pragma unroll
        for (int i = 0; i < 8; ++i)
          mx[i] = fmaxf(fmaxf(aL0[i], aL0[i + 8]), fmaxf(aL1[i], aL1[i + 8]));
#pragma unroll
        for (int i = 0; i < 4; ++i) mx[i] = fmaxf(mx[i], mx[i + 4]);
        const float mloc = fmaxf(fmaxf(mx[0], mx[1]), fmaxf(mx[2], mx[3]));
        const uintx2 mp = __builtin_amdgcn_permlane32_swap(__float_as_uint(mloc), __float_as_uint(mloc), false, false);
        const float pm = fmaxf(__uint_as_float(mp.x), __uint_as_float(mp.y));
        const bool grow = pm > mA + 8.0f;
        if (__any(grow)) {
          const float mn = grow ? pm : mA;
          const float alpha = __builtin_amdgcn_exp2f(mA - mn);
          mA = mn; lA *= alpha;
#pragma unroll
          for (int i = 0; i < 16; ++i) { oA0[i] *= alpha; oA1[i] *= alpha; }
        }
#pragma unroll
        for (int i = 0; i < 16; ++i) {
          p0[i] = __builtin_amdgcn_exp2f(aL0[i] - mA);
          p1[i] = __builtin_amdgcn_exp2f(aL1[i] - mA);
        }
        unsigned W0 = cvtpk_bf16(p0[0], p0[1]), W1 = cvtpk_bf16(p0[2], p0[3]);
        unsigned W2 = cvtpk_bf16(p0[4], p0[5]), W3 = cvtpk_bf16(p0[6], p0[7]);
        uintx2 Aa = __builtin_amdgcn_permlane32_swap(W0, W2, false, false);
        uintx2 Ab = __builtin_amdgcn_permlane32_swap(W1, W3, false, false);
        { union { unsigned u[4]; bf16x8 v; } t = {{Aa.x, Ab.x, Aa.y, Ab.y}}; pfL0 = t.v; }
        W0 = cvtpk_bf16(p0[8], p0[9]);   W1 = cvtpk_bf16(p0[10], p0[11]);
        W2 = cvtpk_bf16(p0[12], p0[13]); W3 = cvtpk_bf16(p0[14], p0[15]);
        Aa = __builtin_amdgcn_permlane32_swap(W0, W2, false, false);
        Ab = __builtin_amdgcn_permlane32_swap(W1, W3, false, false);
        { union { unsigned u[4]; bf16x8 v; } t = {{Aa.x, Ab.x, Aa.y, Ab.y}}; pfL1 = t.v; }
        W0 = cvtpk_bf16(p1[0], p1[1]);   W1 = cvtpk_bf16(p1[2], p1[3]);
        W2 = cvtpk_bf16(p1[4], p1[5]);   W3 = cvtpk_bf16(p1[6], p1[7]);
        Aa = __builtin_amdgcn_permlane32_swap(W0, W2, false, false);
        Ab = __builtin_amdgcn_permlane32_swap(W1, W3, false, false);
        { union { unsigned u[4]; bf16x8 v; } t = {{Aa.x, Ab.x, Aa.y, Ab.y}}; pfL2 = t.v; }
        W0 = cvtpk_bf16(p1[8], p1[9]);   W1 = cvtpk_bf16(p1[10], p1[11]);
        W2 = cvtpk_bf16(p1[12], p1[13]); W3 = cvtpk_bf16(p1[14], p1[15]);
        Aa = __builtin_amdgcn_permlane32_swap(W0, W2, false, false);
        Ab = __builtin_amdgcn_permlane32_swap(W1, W3, false, false);
        { union { unsigned u[4]; bf16x8 v; } t = {{Aa.x, Ab.x, Aa.y, Ab.y}}; pfL3 = t.v; }
        float sm[8];
#pragma unroll
        for (int i = 0; i < 8; ++i) sm[i] = (p0[i] + p0[i + 8]) + (p1[i] + p1[i + 8]);
#pragma unroll
        for (int i = 0; i < 4; ++i) sm[i] = sm[i] + sm[i + 4];
        const float sloc = (sm[0] + sm[1]) + (sm[2] + sm[3]);
        const uintx2 sp = __builtin_amdgcn_permlane32_swap(__float_as_uint(sloc), __float_as_uint(sloc), false, false);
        lA += __uint_as_float(sp.x) + __uint_as_float(sp.y);
      }
      // ---- softmax hi-half ----
      {
        float mx[8];
#pragma unroll
        for (int i = 0; i < 8; ++i)
          mx[i] = fmaxf(fmaxf(aH0[i], aH0[i + 8]), fmaxf(aH1[i], aH1[i + 8]));
#pragma unroll
        for (int i = 0; i < 4; ++i) mx[i] = fmaxf(mx[i], mx[i + 4]);
        const float mloc = fmaxf(fmaxf(mx[0], mx[1]), fmaxf(mx[2], mx[3]));
        const uintx2 mp = __builtin_amdgcn_permlane32_swap(__float_as_uint(mloc), __float_as_uint(mloc), false, false);
        const float pm = fmaxf(__uint_as_float(mp.x), __uint_as_float(mp.y));
        const bool grow = pm > mB + 8.0f;
        if (__any(grow)) {
          const float mn = grow ? pm : mB;
          const float alpha = __builtin_amdgcn_exp2f(mB - mn);
          mB = mn; lB *= alpha;
#pragma unroll
          for (int i = 0; i < 16; ++i) { oB0[i] *= alpha; oB1[i] *= alpha; }
        }
#pragma unroll
        for (int i = 0; i < 16; ++i) {
          p0[i] = __builtin_amdgcn_exp2f(aH0[i] - mB);
          p1[i] = __builtin_amdgcn_exp2f(aH1[i] - mB);
        }
        unsigned W0 = cvtpk_bf16(p0[0], p0[1]), W1 = cvtpk_bf16(p0[2], p0[3]);
        unsigned W2 = cvtpk_bf16(p0[4], p0[5]), W3 = cvtpk_bf16(p0[6], p0[7]);
        uintx2 Aa = __builtin_amdgcn_permlane32_swap(W0, W2, false, false);
        uintx2 Ab = __builtin_amdgcn_permlane32_swap(W1, W3, false, false);
        { union { unsigned u[4]; bf16x8 v; } t = {{Aa.x, Ab.x, Aa.y, Ab.y}}; pfH0 = t.v; }
        W0 = cvtpk_bf16(p0[8], p0[9]);   W1 = cvtpk_bf16(p0[10], p0[11]);
        W2 = cvtpk_bf16(p0[12], p0[13]); W3 = cvtpk_bf16(p0[14], p0[15]);
        Aa = __builtin_amdgcn_permlane32_swap(W0, W2, false, false);
        Ab = __builtin_amdgcn_permlane32_swap(W1, W3, false, false);
        { union { unsigned u[4]; bf16x8 v; } t = {{Aa.x, Ab.x, Aa.y, Ab.y}}; pfH1 = t.v; }
        W0 = cvtpk_bf16(p1[0], p1[1]);   W1 = cvtpk_bf16(p1[2], p1[3]);
        W2 = cvtpk_bf16(p1[4], p1[5]);   W3 = cvtpk_bf16(p1[6], p1[7]);
        Aa = __builtin_amdgcn_permlane32_swap(W0, W2, false, false);
        Ab = __builtin_amdgcn_permlane32_swap(W1, W3, false, false);
        { union { unsigned u[4]; bf16x8 v; } t = {{Aa.x, Ab.x, Aa.y, Ab.y}}; pfH2 = t.v; }
        W0 = cvtpk_bf16(p1[8], p1[9]);   W1 = cvtpk_bf16(p1[10], p1[11]);
        W2 = cvtpk_bf16(p1[12], p1[13]); W3 = cvtpk_bf16(p1[14], p1[15]);
        Aa = __builtin_amdgcn_permlane32_swap(W0, W2, false, false);
        Ab = __builtin_amdgcn_permlane32_swap(W1, W3, false, false);
        { union { unsigned u[4]; bf16x8 v; } t = {{Aa.x, Ab.x, Aa.y, Ab.y}}; pfH3 = t.v; }
        float sm[8];
#pragma unroll
        for (int i = 0; i < 8; ++i) sm[i] = (p0[i] + p0[i + 8]) + (p1[i] + p1[i + 8]);
#pragma unroll
        for (int i = 0; i < 4; ++i) sm[i] = sm[i] + sm[i + 4];
        const float sloc = (sm[0] + sm[1]) + (sm[2] + sm[3]);
        const uintx2 sp = __builtin_amdgcn_permlane32_swap(__float_as_uint(sloc), __float_as_uint(sloc), false, false);
        lB += __uint_as_float(sp.x) + __uint_as_float(sp.y);
      }
      // ---- PV: V frags read once, used for both halves ----
      __builtin_amdgcn_s_setprio(1);
#pragma unroll
      for (int dt = 0; dt < 2; ++dt) {
        const int rowb = (dt * 32 + lq) * 64;
        const bf16x8 vf0 = *(const bf16x8*)(&VL[rowb + ((0 * 2 + hi) ^ swz) * 8]);
        const bf16x8 vf1 = *(const bf16x8*)(&VL[rowb + ((1 * 2 + hi) ^ swz) * 8]);
        const bf16x8 vf2 = *(const bf16x8*)(&VL[rowb + ((2 * 2 + hi) ^ swz) * 8]);
        const bf16x8 vf3 = *(const bf16x8*)(&VL[rowb + ((3 * 2 + hi) ^ swz) * 8]);
        if (dt == 0) {
          oA0 = __builtin_amdgcn_mfma_f32_32x32x16_bf16(vf0, pfL0, oA0, 0, 0, 0);
          oA0 = __builtin_amdgcn_mfma_f32_32x32x16_bf16(vf1, pfL1, oA0, 0, 0, 0);
          oA0 = __builtin_amdgcn_mfma_f32_32x32x16_bf16(vf2, pfL2, oA0, 0, 0, 0);
          oA0 = __builtin_amdgcn_mfma_f32_32x32x16_bf16(vf3, pfL3, oA0, 0, 0, 0);
          oB0 = __builtin_amdgcn_mfma_f32_32x32x16_bf16(vf0, pfH0, oB0, 0, 0, 0);
          oB0 = __builtin_amdgcn_mfma_f32_32x32x16_bf16(vf1, pfH1, oB0, 0, 0, 0);
          oB0 = __builtin_amdgcn_mfma_f32_32x32x16_bf16(vf2, pfH2, oB0, 0, 0, 0);
          oB0 = __builtin_amdgcn_mfma_f32_32x32x16_bf16(vf3, pfH3, oB0, 0, 0, 0);
        } else {
          oA1 = __builtin_amdgcn_mfma_f32_32x32x16_bf16(vf0, pfL0, oA1, 0, 0, 0);
          oA1 = __builtin_amdgcn_mfma_f32_32x32x16_bf16(vf1, pfL1, oA1, 0, 0, 0);
          oA1 = __builtin_amdgcn_mfma_f32_32x32x16_bf16(vf2, pfL2, oA1, 0, 0, 0);
          oA1 = __builtin_amdgcn_mfma_f32_32x32x16_bf16(vf3, pfL3, oA1, 0, 0, 0);
          oB1 = __builtin_amdgcn_mfma_f32_32x32x16_bf16(vf0, pfH0, oB1, 0, 0, 0);
          oB1 = __builtin_amdgcn_mfma_f32_32x32x16_bf16(vf1, pfH1, oB1, 0, 0, 0);
          oB1 = __builtin_amdgcn_mfma_f32_32x32x16_bf16(vf2, pfH2, oB1, 0, 0, 0);
          oB1 = __builtin_amdgcn_mfma_f32_32x32x16_bf16(vf3, pfH3, oB1, 0, 0, 0);
        }
      }
      __builtin_amdgcn_s_setprio(0);
    }
  }
  asm volatile("s_waitcnt vmcnt(0)" ::: "memory");   // drain trailing prefetch
  __builtin_amdgcn_s_barrier();                      // all compute done; reuse shm

  // ---- write partials: mbuf[strip][wave][lane][36] (bf16), mstat (f32) ----
  {
#pragma unroll
    for (int s2 = 0; s2 < 2; ++s2) {
      unsigned short* prow = &shm[((s2 * 4 + w) * 64 + l) * 36];
      ushortx4 t0;
#pragma unroll
      for (int s4 = 0; s4 < 4; ++s4) {
#pragma unroll
        for (int i = 0; i < 4; ++i) t0[i] = f2bf(s2 ? oB0[s4 * 4 + i] : oA0[s4 * 4 + i]);
        *(ushortx4*)(prow + s4 * 4) = t0;
      }
#pragma unroll
      for (int s4 = 0; s4 < 4; ++s4) {
#pragma unroll
        for (int i = 0; i < 4; ++i) t0[i] = f2bf(s2 ? oB1[s4 * 4 + i] : oA1[s4 * 4 + i]);
        *(ushortx4*)(prow + 16 + s4 * 4) = t0;
      }
    }
    if (hi == 0) {
      mstat[0][0][w][lq] = mA; mstat[0][1][w][lq] = lA;
      mstat[1][0][w][lq] = mB; mstat[1][1][w][lq] = lB;
    }
  }
  __syncthreads();

  // ---- distributed 4-way merge per strip; wave w merges reg-slice w ----
  const int b = bh >> 4, hh = bh & 15;
#pragma unroll
  for (int s2 = 0; s2 < 2; ++s2) {
    float mw[4], lw[4];
#pragma unroll
    for (int w2 = 0; w2 < 4; ++w2) { mw[w2] = mstat[s2][0][w2][lq]; lw[w2] = mstat[s2][1][w2][lq]; }
    const float M = fmaxf(fmaxf(mw[0], mw[1]), fmaxf(mw[2], mw[3]));
    float fw[4], L = 0.f;
#pragma unroll
    for (int w2 = 0; w2 < 4; ++w2) { fw[w2] = __builtin_amdgcn_exp2f(mw[w2] - M); L += lw[w2] * fw[w2]; }
    float a0[4] = {0.f, 0.f, 0.f, 0.f}, a1[4] = {0.f, 0.f, 0.f, 0.f};
#pragma unroll
    for (int w2 = 0; w2 < 4; ++w2) {
      const unsigned short* prow = &shm[((s2 * 4 + w2) * 64 + l) * 36];
      const ushortx4 pa = *(const ushortx4*)(prow + w * 4);
      const ushortx4 pb = *(const ushortx4*)(prow + 16 + w * 4);
#pragma unroll
      for (int i = 0; i < 4; ++i) {
        a0[i] += fw[w2] * bf2f(pa[i]);
        a1[i] += fw[w2] * bf2f(pb[i]);
      }
    }
    const float rl = __builtin_amdgcn_rcpf(L);
    unsigned short* orow = Ob + (size_t)(b * T_ + q0 + s2 * 32 + lq) * C_ + hh * D_ + 4 * hi;
    ushortx4 ov0, ov1;
#pragma unroll
    for (int i = 0; i < 4; ++i) { ov0[i] = f2bf(a0[i] * rl); ov1[i] = f2bf(a1[i] * rl); }
    *(ushortx4*)(orow + w * 8) = ov0;
    *(ushortx4*)(orow + 32 + w * 8) = ov1;
  }
}

// ---------------- launch ----------------
extern "C" void kernel_launch(void* const* d_in, const int* in_sizes, int n_in,
                              void* d_out, int out_size, void* d_ws, size_t ws_size,
                              hipStream_t stream) {
  const float* x = (const float*)d_in[0];
  const float* Wqkv = (const float*)d_in[1];
  const float* Wout = (const float*)d_in[2];
  float* out = (float*)d_out;
  char* ws = (char*)d_ws;
  // workspace layout (72 MiB total)
  unsigned short* Xb    = (unsigned short*)(ws);                  //  8 MiB [4096][1024]
  unsigned short* WqkvT = (unsigned short*)(ws + (8ull << 20));   //  6 MiB [3072][1024]
  unsigned short* WoutT = (unsigned short*)(ws + (14ull << 20));  //  2 MiB [1024][1024]
  unsigned short* QKVb  = (unsigned short*)(ws + (16ull << 20));  // 24 MiB [4096][3072]
  unsigned short* Qp    = (unsigned short*)(ws + (40ull << 20));  //  8 MiB [32][2048][64]
  unsigned short* Kp    = (unsigned short*)(ws + (48ull << 20));  //  8 MiB
  unsigned short* Vt    = (unsigned short*)(ws + (56ull << 20));  //  8 MiB [32][64][2048]
  unsigned short* Ob    = (unsigned short*)(ws + (64ull << 20));  //  8 MiB [4096][1024]

  prep_kernel<<<8192, 256, 0, stream>>>(x, Xb, Wqkv, WqkvT, Wout, WoutT);
  gemm_bt_kernel<0><<<dim3(N3_ / 128, (B_ * T_) / 128), 256, 0, stream>>>(
      Xb, WqkvT, QKVb, B_ * T_, N3_, C_);
  rope_vtrans_kernel<<<dim3(T_ / 64, B_ * H_, 2), 256, 0, stream>>>(QKVb, Qp, Kp, Vt);
  attn8_kernel<<<1024, 256, 0, stream>>>(Qp, Kp, Vt, Ob);
  gemm_bt_kernel<1><<<dim3(C_ / 128, (B_ * T_) / 128), 256, 0, stream>>>(
      Ob, WoutT, out, B_ * T_, C_, C_);
}

// Round 13
// 118.399 us; speedup vs baseline: 1.2595x; 1.2595x over previous
//
#include <hip/hip_runtime.h>

// Problem: CausalSelfAttention  B=2 T=2048 C=1024 H=16 D=64, fp32 in/out.
// Pipeline: prep(cvt+tconv+tconv fused) -> GEMM1(128^2 bf16) -> rope+vtrans(fused)
//           -> attn9 (adjacent strips + 3-buf counted-vmcnt + paired dispatch) -> GEMM2.

#define B_  2
#define T_  2048
#define C_  1024
#define H_  16
#define D_  64
#define N3_ 3072

typedef unsigned short ushortx8 __attribute__((ext_vector_type(8)));
typedef unsigned short ushortx4 __attribute__((ext_vector_type(4)));
typedef short bf16x8 __attribute__((ext_vector_type(8)));
typedef float f32x4 __attribute__((ext_vector_type(4)));
typedef float f32x16 __attribute__((ext_vector_type(16)));
typedef unsigned int uintx2 __attribute__((ext_vector_type(2)));

__device__ __forceinline__ unsigned short f2bf(float f) {
  union { float f; unsigned u; } v; v.f = f;
  unsigned r = v.u + 0x7FFFu + ((v.u >> 16) & 1u);   // RNE
  return (unsigned short)(r >> 16);
}
__device__ __forceinline__ float bf2f(unsigned short h) {
  union { unsigned u; float f; } v; v.u = ((unsigned)h) << 16;
  return v.f;
}
// pack two f32 -> 2xbf16 in one u32 (no builtin exists; m240)
__device__ __forceinline__ unsigned cvtpk_bf16(float lo, float hi) {
  unsigned r; asm("v_cvt_pk_bf16_f32 %0, %1, %2" : "=v"(r) : "v"(lo), "v"(hi));
  return r;
}
// async global->LDS, 16B per lane; dst must be wave-uniform (HW adds lane*16)
__device__ __forceinline__ void gload_lds16(const void* g, void* l) {
  __builtin_amdgcn_global_load_lds((const __attribute__((address_space(1))) void*)g,
                                   (__attribute__((address_space(3))) void*)l,
                                   16, 0, 0);
}

// ---- fused prep: blocks [0,4096) cvt x->bf16; [4096,7168) tconv Wqkv; [7168,8192) tconv Wout
__global__ __launch_bounds__(256) void prep_kernel(const float* __restrict__ x,
                                                   unsigned short* __restrict__ Xb,
                                                   const float* __restrict__ Wqkv,
                                                   unsigned short* __restrict__ WqkvT,
                                                   const float* __restrict__ Wout,
                                                   unsigned short* __restrict__ WoutT) {
  __shared__ float tile[32][33];
  const int bid = blockIdx.x;
  if (bid < 4096) {
    size_t i = ((size_t)bid * 256 + threadIdx.x) * 4;
    const float4 v = *(const float4*)(x + i);
    ushortx4 o;
    o[0] = f2bf(v.x); o[1] = f2bf(v.y); o[2] = f2bf(v.z); o[3] = f2bf(v.w);
    *(ushortx4*)(Xb + i) = o;
    return;
  }
  const float* W;
  unsigned short* WT;
  int K, N, n0, k0;
  if (bid < 7168) {
    const int idx = bid - 4096;
    W = Wqkv; WT = WqkvT; K = C_; N = N3_;
    n0 = (idx % (N3_ / 32)) * 32; k0 = (idx / (N3_ / 32)) * 32;
  } else {
    const int idx = bid - 7168;
    W = Wout; WT = WoutT; K = C_; N = C_;
    n0 = (idx % (C_ / 32)) * 32; k0 = (idx / (C_ / 32)) * 32;
  }
  const int tx = threadIdx.x & 31, ty = threadIdx.x >> 5;
#pragma unroll
  for (int i = 0; i < 4; ++i)
    tile[ty + i * 8][tx] = W[(size_t)(k0 + ty + i * 8) * N + n0 + tx];
  __syncthreads();
#pragma unroll
  for (int i = 0; i < 4; ++i)
    WT[(size_t)(n0 + ty + i * 8) * K + k0 + tx] = f2bf(tile[tx][ty + i * 8]);
}

// ---------------- GEMM: C[M][N] = A[M][K] * BT[N][K]^T (bf16 MFMA) ----------------
// 128x128 tile, BK=64, 4 waves (each 64x64), global_load_lds w/ XOR-swizzled source.
template <int OUTF32>
__global__ __launch_bounds__(256) void gemm_bt_kernel(const unsigned short* __restrict__ A,
                                                      const unsigned short* __restrict__ BT,
                                                      void* __restrict__ Cptr,
                                                      int M, int N, int K) {
  __shared__ unsigned short Alds[128 * 64];
  __shared__ unsigned short Blds[128 * 64];
  const int tid = threadIdx.x;
  const int w = tid >> 6, l = tid & 63;
  const int wr = w >> 1, wc = w & 1;
  const int lg = l >> 4, lr = l & 15;
  const int m0 = blockIdx.y * 128, n0 = blockIdx.x * 128;
  const int lr8 = l >> 3;                 // row within 8-row chunk
  const int lc8 = (l & 7) ^ lr8;          // pre-swizzled source col16 (T2 st-style)

  f32x4 acc[4][4];
#pragma unroll
  for (int i = 0; i < 4; ++i)
#pragma unroll
    for (int j = 0; j < 4; ++j) acc[i][j] = f32x4{0.f, 0.f, 0.f, 0.f};

  for (int k0 = 0; k0 < K; k0 += 64) {
    __syncthreads();
#pragma unroll
    for (int i = 0; i < 4; ++i) {
      const int ch = w * 4 + i;           // 16 chunks of 1024B per tile
      gload_lds16(A + (size_t)(m0 + ch * 8 + lr8) * K + k0 + lc8 * 8, &Alds[ch * 512]);
      gload_lds16(BT + (size_t)(n0 + ch * 8 + lr8) * K + k0 + lc8 * 8, &Blds[ch * 512]);
    }
    __syncthreads();
#pragma unroll
    for (int kc = 0; kc < 2; ++kc) {
      bf16x8 af[4], bfr[4];
#pragma unroll
      for (int mi = 0; mi < 4; ++mi) {
        const int row = wr * 64 + mi * 16 + lr;
        const int c16 = (kc * 4 + lg) ^ (row & 7);
        af[mi] = *(const bf16x8*)(&Alds[row * 64 + c16 * 8]);
      }
#pragma unroll
      for (int nj = 0; nj < 4; ++nj) {
        const int row = wc * 64 + nj * 16 + lr;
        const int c16 = (kc * 4 + lg) ^ (row & 7);
        bfr[nj] = *(const bf16x8*)(&Blds[row * 64 + c16 * 8]);
      }
#pragma unroll
      for (int mi = 0; mi < 4; ++mi)
#pragma unroll
        for (int nj = 0; nj < 4; ++nj)
          acc[mi][nj] = __builtin_amdgcn_mfma_f32_16x16x32_bf16(af[mi], bfr[nj], acc[mi][nj], 0, 0, 0);
    }
  }
#pragma unroll
  for (int mi = 0; mi < 4; ++mi)
#pragma unroll
    for (int nj = 0; nj < 4; ++nj)
#pragma unroll
      for (int j = 0; j < 4; ++j) {
        const int row = m0 + wr * 64 + mi * 16 + lg * 4 + j;  // C/D: row=(lane>>4)*4+j
        const int col = n0 + wc * 64 + nj * 16 + lr;          //      col=lane&15
        if (OUTF32) ((float*)Cptr)[(size_t)row * N + col] = acc[mi][nj][j];
        else ((unsigned short*)Cptr)[(size_t)row * N + col] = f2bf(acc[mi][nj][j]);
      }
}

// ---- fused RoPE-pack (z=0) + V-transpose (z=1) ----
__global__ __launch_bounds__(256) void rope_vtrans_kernel(const unsigned short* __restrict__ QKV,
                                                          unsigned short* __restrict__ Qp,
                                                          unsigned short* __restrict__ Kp,
                                                          unsigned short* __restrict__ Vt) {
  __shared__ unsigned short tile[64][72];
  const int tt = blockIdx.x, bh = blockIdx.y;
  const int b = bh >> 4, h = bh & 15;
  const int tid = threadIdx.x;
  if (blockIdx.z == 0) {
    const int half = tid >> 7;           // 0=q, 1=k
    const int r = (tid >> 1) & 63;
    const int d0 = (tid & 1) * 16;
    const int t = tt * 64 + r;
    const unsigned short* src = QKV + (size_t)(b * T_ + t) * N3_ + half * C_ + h * D_;
    ushortx8 lo0 = *(const ushortx8*)(src + d0);
    ushortx8 lo1 = *(const ushortx8*)(src + d0 + 8);
    ushortx8 hi0 = *(const ushortx8*)(src + d0 + 32);
    ushortx8 hi1 = *(const ushortx8*)(src + d0 + 40);
    ushortx8 olo0, olo1, ohi0, ohi1;
    const float scale = half ? 1.0f : 0.18033688011112042f;
    const float tf = (float)t;
#pragma unroll
    for (int jj = 0; jj < 16; ++jj) {
      const int d = d0 + jj;
      const float invf = exp2f((float)d * -0.41524101186092036f);
      const float ang = tf * invf;
      const float c = cosf(ang), s = sinf(ang);
      const float xl = bf2f(jj < 8 ? lo0[jj] : lo1[jj - 8]);
      const float xh = bf2f(jj < 8 ? hi0[jj] : hi1[jj - 8]);
      const unsigned short rl = f2bf((xl * c - xh * s) * scale);
      const unsigned short rh = f2bf((xh * c + xl * s) * scale);
      if (jj < 8) { olo0[jj] = rl; ohi0[jj] = rh; }
      else        { olo1[jj - 8] = rl; ohi1[jj - 8] = rh; }
    }
    unsigned short* dst = (half ? Kp : Qp) + ((size_t)bh * T_ + t) * D_;
    *(ushortx8*)(dst + d0) = olo0;
    *(ushortx8*)(dst + d0 + 8) = olo1;
    *(ushortx8*)(dst + d0 + 32) = ohi0;
    *(ushortx8*)(dst + d0 + 40) = ohi1;
  } else {
    {
      const int r = tid >> 2, seg = tid & 3;
      const unsigned short* src = QKV + (size_t)(b * T_ + tt * 64 + r) * N3_ + 2 * C_ + h * D_ + seg * 16;
      *(ushortx8*)(&tile[r][seg * 16]) = *(const ushortx8*)(src);
      *(ushortx8*)(&tile[r][seg * 16 + 8]) = *(const ushortx8*)(src + 8);
    }
    __syncthreads();
    {
      const int d = tid >> 2, ts = tid & 3;
      ushortx8 o0, o1;
#pragma unroll
      for (int i = 0; i < 8; ++i) { o0[i] = tile[ts * 16 + i][d]; o1[i] = tile[ts * 16 + 8 + i][d]; }
      unsigned short* dst = Vt + ((size_t)bh * D_ + d) * T_ + tt * 64 + ts * 16;
      *(ushortx8*)(dst) = o0;
      *(ushortx8*)(dst + 8) = o1;
    }
  }
}

// -------- causal flash attention v9: adjacent strips + paired dispatch --------
// Block g covers strips {4g, 4g+1, 4g+2, 4g+3} (wave w <-> strip 4g+w), so all
// waves are active ~every iteration and ntiles = 2g+2 is minimal for the group.
// Dispatch map: first 256 blocks g=15..8 (long, one per CU), second 256 blocks
// g=0..7 -> per-CU pair (g, 15-g) sums to 34 iterations, constant, co-resident.
// Staging: attn7's 3-buffer ring + counted s_waitcnt vmcnt(4) (loads stay in
// flight across the barrier); compute body identical to attn6/7 (proven).
__global__ __launch_bounds__(256, 2) void attn9_kernel(const unsigned short* __restrict__ Qp,
                                                       const unsigned short* __restrict__ Kp,
                                                       const unsigned short* __restrict__ Vt,
                                                       unsigned short* __restrict__ Ob) {
  __shared__ unsigned short Klds[3][64 * 64];   // [buf][kv][d]   8KB each
  __shared__ unsigned short Vlds[3][64 * 64];   // [buf][d][kv]   8KB each
  const int tid = threadIdx.x, w = tid >> 6, l = tid & 63;
  const int lq = l & 31, hi = l >> 5;
  const int swz = lq & 7;
  const int bid = blockIdx.x;
  const int bh = bid & 31;                      // same head -> same XCD (bid%8)
  const int j = bid >> 5;                       // 0..15
  const int g = (j < 8) ? (15 - j) : (j - 8);   // round1: g=15..8; round2: g=0..7
  const int s = 4 * g + w;                      // this wave's strip
  const int q0 = s * 32;
  const int ntiles = 2 * g + 2;                 // tiles needed by strip 4g+3
  const size_t koff = (size_t)bh * T_ * D_;
  const unsigned short* Kb = Kp + koff;
  const unsigned short* Vb = Vt + (size_t)bh * D_ * T_;

  const int lr8 = l >> 3;               // staging: row within 8-row chunk
  const int lc8 = (l & 7) ^ lr8;        // pre-swizzled source 16B slot

  // Q B-frags: lane holds Q[q0+lq][ds*16 + hi*8 + j]
  bf16x8 qf[4];
  {
    const unsigned short* qp = Qp + koff + (size_t)(q0 + lq) * D_ + hi * 8;
#pragma unroll
    for (int ds = 0; ds < 4; ++ds) qf[ds] = *(const bf16x8*)(qp + ds * 16);
  }
  f32x16 o0, o1;
#pragma unroll
  for (int r = 0; r < 16; ++r) { o0[r] = 0.f; o1[r] = 0.f; }
  float m = -3.0e38f, lden = 0.f;

  // prologue: stage tile 0 into buf 0 (wave w stages chunks 2w, 2w+1)
#pragma unroll
  for (int i = 0; i < 2; ++i) {
    const int c = w * 2 + i;
    gload_lds16(Kb + (size_t)(c * 8 + lr8) * D_ + lc8 * 8, &Klds[0][c * 512]);
    gload_lds16(Vb + (size_t)(c * 8 + lr8) * T_ + lc8 * 8, &Vlds[0][c * 512]);
  }

  for (int kt = 0; kt < ntiles; ++kt) {
    const int cur = kt % 3;
    const int nxt = (kt + 1) % 3;
    // issue next-tile loads (clamped: last iter re-stages into an unread buf)
    const int ktn = (kt + 1 < ntiles) ? kt + 1 : kt;
    const int kvn = ktn * 64;
#pragma unroll
    for (int i = 0; i < 2; ++i) {
      const int c = w * 2 + i;
      gload_lds16(Kb + (size_t)(kvn + c * 8 + lr8) * D_ + lc8 * 8, &Klds[nxt][c * 512]);
      gload_lds16(Vb + (size_t)(c * 8 + lr8) * T_ + kvn + lc8 * 8, &Vlds[nxt][c * 512]);
    }
    // tile kt's 4 loads land (leave next tile's 4 in flight), then sync waves
    asm volatile("s_waitcnt vmcnt(4)" ::: "memory");
    __builtin_amdgcn_s_barrier();
    __builtin_amdgcn_sched_barrier(0);

    const int kv0 = kt * 64;
    if (kv0 <= q0 + 31) {   // wave-uniform: tile intersects causal range
      const unsigned short* KL = &Klds[cur][0];
      const unsigned short* VL = &Vlds[cur][0];
      // S^T = K . Q^T over d=64, two 32-kv groups
      f32x16 acc0, acc1;
#pragma unroll
      for (int r = 0; r < 16; ++r) { acc0[r] = 0.f; acc1[r] = 0.f; }
      __builtin_amdgcn_s_setprio(1);
#pragma unroll
      for (int ds = 0; ds < 4; ++ds) {
        const int slot = ((ds * 2 + hi) ^ swz) * 8;
        const bf16x8 kf0 = *(const bf16x8*)(&KL[(lq) * 64 + slot]);
        const bf16x8 kf1 = *(const bf16x8*)(&KL[(32 + lq) * 64 + slot]);
        acc0 = __builtin_amdgcn_mfma_f32_32x32x16_bf16(kf0, qf[ds], acc0, 0, 0, 0);
        acc1 = __builtin_amdgcn_mfma_f32_32x32x16_bf16(kf1, qf[ds], acc1, 0, 0, 0);
      }
      __builtin_amdgcn_s_setprio(0);
      if (kv0 + 63 > q0) {   // diagonal tile(s): mask kv_global > q_global
        const int thr0 = q0 + lq - kv0;
        const int thr1 = thr0 - 32;
#pragma unroll
        for (int r = 0; r < 16; ++r) {
          const int kvloc = (r & 3) + 8 * (r >> 2) + 4 * hi;
          if (kvloc > thr0) acc0[r] = -3.0e38f;
          if (kvloc > thr1) acc1[r] = -3.0e38f;
        }
      }
      // in-lane max over 32 + cross-half permlane swap
      float mx[8];
#pragma unroll
      for (int i = 0; i < 8; ++i)
        mx[i] = fmaxf(fmaxf(acc0[i], acc0[i + 8]), fmaxf(acc1[i], acc1[i + 8]));
#pragma unroll
      for (int i = 0; i < 4; ++i) mx[i] = fmaxf(mx[i], mx[i + 4]);
      const float mloc = fmaxf(fmaxf(mx[0], mx[1]), fmaxf(mx[2], mx[3]));
      const uintx2 mp = __builtin_amdgcn_permlane32_swap(__float_as_uint(mloc), __float_as_uint(mloc), false, false);
      const float pm = fmaxf(__uint_as_float(mp.x), __uint_as_float(mp.y));
      // defer-max (T13): rescale only when max grew by > 8
      const bool grow = pm > m + 8.0f;
      if (__any(grow)) {
        const float mn = grow ? pm : m;
        const float alpha = __builtin_amdgcn_exp2f(m - mn);
        m = mn;
        lden *= alpha;
#pragma unroll
        for (int r = 0; r < 16; ++r) { o0[r] *= alpha; o1[r] *= alpha; }
      }
      float p0[16], p1[16];
#pragma unroll
      for (int r = 0; r < 16; ++r) {
        p0[r] = __builtin_amdgcn_exp2f(acc0[r] - m);
        p1[r] = __builtin_amdgcn_exp2f(acc1[r] - m);
      }
      // P -> B-frags (T12): cvt_pk pairs, permlane32_swap x-hi <-> y-lo
      unsigned W0 = cvtpk_bf16(p0[0], p0[1]), W1 = cvtpk_bf16(p0[2], p0[3]);
      unsigned W2 = cvtpk_bf16(p0[4], p0[5]), W3 = cvtpk_bf16(p0[6], p0[7]);
      uintx2 Aa = __builtin_amdgcn_permlane32_swap(W0, W2, false, false);
      uintx2 Ab = __builtin_amdgcn_permlane32_swap(W1, W3, false, false);
      union { unsigned u[4]; bf16x8 v; } pfa0 = {{Aa.x, Ab.x, Aa.y, Ab.y}};
      W0 = cvtpk_bf16(p0[8], p0[9]);   W1 = cvtpk_bf16(p0[10], p0[11]);
      W2 = cvtpk_bf16(p0[12], p0[13]); W3 = cvtpk_bf16(p0[14], p0[15]);
      Aa = __builtin_amdgcn_permlane32_swap(W0, W2, false, false);
      Ab = __builtin_amdgcn_permlane32_swap(W1, W3, false, false);
      union { unsigned u[4]; bf16x8 v; } pfa1 = {{Aa.x, Ab.x, Aa.y, Ab.y}};
      W0 = cvtpk_bf16(p1[0], p1[1]);   W1 = cvtpk_bf16(p1[2], p1[3]);
      W2 = cvtpk_bf16(p1[4], p1[5]);   W3 = cvtpk_bf16(p1[6], p1[7]);
      Aa = __builtin_amdgcn_permlane32_swap(W0, W2, false, false);
      Ab = __builtin_amdgcn_permlane32_swap(W1, W3, false, false);
      union { unsigned u[4]; bf16x8 v; } pfb0 = {{Aa.x, Ab.x, Aa.y, Ab.y}};
      W0 = cvtpk_bf16(p1[8], p1[9]);   W1 = cvtpk_bf16(p1[10], p1[11]);
      W2 = cvtpk_bf16(p1[12], p1[13]); W3 = cvtpk_bf16(p1[14], p1[15]);
      Aa = __builtin_amdgcn_permlane32_swap(W0, W2, false, false);
      Ab = __builtin_amdgcn_permlane32_swap(W1, W3, false, false);
      union { unsigned u[4]; bf16x8 v; } pfb1 = {{Aa.x, Ab.x, Aa.y, Ab.y}};

      // O^T += V^T . P^T  (kv slices: 0-15=pfa0, 16-31=pfa1, 32-47=pfb0, 48-63=pfb1)
      __builtin_amdgcn_s_setprio(1);
#pragma unroll
      for (int dt = 0; dt < 2; ++dt) {
        const int rowb = (dt * 32 + lq) * 64;
        const bf16x8 vf0 = *(const bf16x8*)(&VL[rowb + ((0 * 2 + hi) ^ swz) * 8]);
        const bf16x8 vf1 = *(const bf16x8*)(&VL[rowb + ((1 * 2 + hi) ^ swz) * 8]);
        const bf16x8 vf2 = *(const bf16x8*)(&VL[rowb + ((2 * 2 + hi) ^ swz) * 8]);
        const bf16x8 vf3 = *(const bf16x8*)(&VL[rowb + ((3 * 2 + hi) ^ swz) * 8]);
        if (dt == 0) {
          o0 = __builtin_amdgcn_mfma_f32_32x32x16_bf16(vf0, pfa0.v, o0, 0, 0, 0);
          o0 = __builtin_amdgcn_mfma_f32_32x32x16_bf16(vf1, pfa1.v, o0, 0, 0, 0);
          o0 = __builtin_amdgcn_mfma_f32_32x32x16_bf16(vf2, pfb0.v, o0, 0, 0, 0);
          o0 = __builtin_amdgcn_mfma_f32_32x32x16_bf16(vf3, pfb1.v, o0, 0, 0, 0);
        } else {
          o1 = __builtin_amdgcn_mfma_f32_32x32x16_bf16(vf0, pfa0.v, o1, 0, 0, 0);
          o1 = __builtin_amdgcn_mfma_f32_32x32x16_bf16(vf1, pfa1.v, o1, 0, 0, 0);
          o1 = __builtin_amdgcn_mfma_f32_32x32x16_bf16(vf2, pfb0.v, o1, 0, 0, 0);
          o1 = __builtin_amdgcn_mfma_f32_32x32x16_bf16(vf3, pfb1.v, o1, 0, 0, 0);
        }
      }
      __builtin_amdgcn_s_setprio(0);
      // lsum trees (overlaps PV on VALU pipe)
      float sm[8];
#pragma unroll
      for (int i = 0; i < 8; ++i) sm[i] = (p0[i] + p0[i + 8]) + (p1[i] + p1[i + 8]);
#pragma unroll
      for (int i = 0; i < 4; ++i) sm[i] = sm[i] + sm[i + 4];
      const float sloc = (sm[0] + sm[1]) + (sm[2] + sm[3]);
      const uintx2 sp = __builtin_amdgcn_permlane32_swap(__float_as_uint(sloc), __float_as_uint(sloc), false, false);
      lden += __uint_as_float(sp.x) + __uint_as_float(sp.y);
    }
  }
  asm volatile("s_waitcnt vmcnt(0)" ::: "memory");   // drain trailing prefetch

  // epilogue: lane holds q=q0+lq, d = dt*32 + rq*8 + 4*hi + i
  const float rl = __builtin_amdgcn_rcpf(lden);
  const int b = bh >> 4, hh = bh & 15;
  unsigned short* orow = Ob + (size_t)(b * T_ + q0 + lq) * C_ + hh * D_ + 4 * hi;
#pragma unroll
  for (int rq = 0; rq < 4; ++rq) {
    ushortx4 ov0, ov1;
#pragma unroll
    for (int i = 0; i < 4; ++i) {
      ov0[i] = f2bf(o0[rq * 4 + i] * rl);
      ov1[i] = f2bf(o1[rq * 4 + i] * rl);
    }
    *(ushortx4*)(orow + rq * 8) = ov0;
    *(ushortx4*)(orow + 32 + rq * 8) = ov1;
  }
}

// ---------------- launch ----------------
extern "C" void kernel_launch(void* const* d_in, const int* in_sizes, int n_in,
                              void* d_out, int out_size, void* d_ws, size_t ws_size,
                              hipStream_t stream) {
  const float* x = (const float*)d_in[0];
  const float* Wqkv = (const float*)d_in[1];
  const float* Wout = (const float*)d_in[2];
  float* out = (float*)d_out;
  char* ws = (char*)d_ws;
  // workspace layout (72 MiB total)
  unsigned short* Xb    = (unsigned short*)(ws);                  //  8 MiB [4096][1024]
  unsigned short* WqkvT = (unsigned short*)(ws + (8ull << 20));   //  6 MiB [3072][1024]
  unsigned short* WoutT = (unsigned short*)(ws + (14ull << 20));  //  2 MiB [1024][1024]
  unsigned short* QKVb  = (unsigned short*)(ws + (16ull << 20));  // 24 MiB [4096][3072]
  unsigned short* Qp    = (unsigned short*)(ws + (40ull << 20));  //  8 MiB [32][2048][64]
  unsigned short* Kp    = (unsigned short*)(ws + (48ull << 20));  //  8 MiB
  unsigned short* Vt    = (unsigned short*)(ws + (56ull << 20));  //  8 MiB [32][64][2048]
  unsigned short* Ob    = (unsigned short*)(ws + (64ull << 20));  //  8 MiB [4096][1024]

  prep_kernel<<<8192, 256, 0, stream>>>(x, Xb, Wqkv, WqkvT, Wout, WoutT);
  gemm_bt_kernel<0><<<dim3(N3_ / 128, (B_ * T_) / 128), 256, 0, stream>>>(
      Xb, WqkvT, QKVb, B_ * T_, N3_, C_);
  rope_vtrans_kernel<<<dim3(T_ / 64, B_ * H_, 2), 256, 0, stream>>>(QKVb, Qp, Kp, Vt);
  attn9_kernel<<<512, 256, 0, stream>>>(Qp, Kp, Vt, Ob);
  gemm_bt_kernel<1><<<dim3(C_ / 128, (B_ * T_) / 128), 256, 0, stream>>>(
      Ob, WoutT, out, B_ * T_, C_, C_);
}

// Round 14
// 114.920 us; speedup vs baseline: 1.2977x; 1.0303x over previous
//
#include <hip/hip_runtime.h>

// Problem: CausalSelfAttention  B=2 T=2048 C=1024 H=16 D=64, fp32 in/out.
// Pipeline: prep(cvt+tconv+tconv fused) -> GEMM1(128^2 bf16) -> rope+vtrans(fused)
//           -> attn10 (KVBLK=128, joint softmax, dbuf counted-vmcnt) -> GEMM2.

#define B_  2
#define T_  2048
#define C_  1024
#define H_  16
#define D_  64
#define N3_ 3072

typedef unsigned short ushortx8 __attribute__((ext_vector_type(8)));
typedef unsigned short ushortx4 __attribute__((ext_vector_type(4)));
typedef short bf16x8 __attribute__((ext_vector_type(8)));
typedef float f32x4 __attribute__((ext_vector_type(4)));
typedef float f32x16 __attribute__((ext_vector_type(16)));
typedef unsigned int uintx2 __attribute__((ext_vector_type(2)));

__device__ __forceinline__ unsigned short f2bf(float f) {
  union { float f; unsigned u; } v; v.f = f;
  unsigned r = v.u + 0x7FFFu + ((v.u >> 16) & 1u);   // RNE
  return (unsigned short)(r >> 16);
}
__device__ __forceinline__ float bf2f(unsigned short h) {
  union { unsigned u; float f; } v; v.u = ((unsigned)h) << 16;
  return v.f;
}
// pack two f32 -> 2xbf16 in one u32 (no builtin exists; m240)
__device__ __forceinline__ unsigned cvtpk_bf16(float lo, float hi) {
  unsigned r; asm("v_cvt_pk_bf16_f32 %0, %1, %2" : "=v"(r) : "v"(lo), "v"(hi));
  return r;
}
// async global->LDS, 16B per lane; dst must be wave-uniform (HW adds lane*16)
__device__ __forceinline__ void gload_lds16(const void* g, void* l) {
  __builtin_amdgcn_global_load_lds((const __attribute__((address_space(1))) void*)g,
                                   (__attribute__((address_space(3))) void*)l,
                                   16, 0, 0);
}

// ---- fused prep: blocks [0,4096) cvt x->bf16; [4096,7168) tconv Wqkv; [7168,8192) tconv Wout
__global__ __launch_bounds__(256) void prep_kernel(const float* __restrict__ x,
                                                   unsigned short* __restrict__ Xb,
                                                   const float* __restrict__ Wqkv,
                                                   unsigned short* __restrict__ WqkvT,
                                                   const float* __restrict__ Wout,
                                                   unsigned short* __restrict__ WoutT) {
  __shared__ float tile[32][33];
  const int bid = blockIdx.x;
  if (bid < 4096) {
    size_t i = ((size_t)bid * 256 + threadIdx.x) * 4;
    const float4 v = *(const float4*)(x + i);
    ushortx4 o;
    o[0] = f2bf(v.x); o[1] = f2bf(v.y); o[2] = f2bf(v.z); o[3] = f2bf(v.w);
    *(ushortx4*)(Xb + i) = o;
    return;
  }
  const float* W;
  unsigned short* WT;
  int K, N, n0, k0;
  if (bid < 7168) {
    const int idx = bid - 4096;
    W = Wqkv; WT = WqkvT; K = C_; N = N3_;
    n0 = (idx % (N3_ / 32)) * 32; k0 = (idx / (N3_ / 32)) * 32;
  } else {
    const int idx = bid - 7168;
    W = Wout; WT = WoutT; K = C_; N = C_;
    n0 = (idx % (C_ / 32)) * 32; k0 = (idx / (C_ / 32)) * 32;
  }
  const int tx = threadIdx.x & 31, ty = threadIdx.x >> 5;
#pragma unroll
  for (int i = 0; i < 4; ++i)
    tile[ty + i * 8][tx] = W[(size_t)(k0 + ty + i * 8) * N + n0 + tx];
  __syncthreads();
#pragma unroll
  for (int i = 0; i < 4; ++i)
    WT[(size_t)(n0 + ty + i * 8) * K + k0 + tx] = f2bf(tile[tx][ty + i * 8]);
}

// ---------------- GEMM: C[M][N] = A[M][K] * BT[N][K]^T (bf16 MFMA) ----------------
// 128x128 tile, BK=64, 4 waves (each 64x64), global_load_lds w/ XOR-swizzled source.
template <int OUTF32>
__global__ __launch_bounds__(256) void gemm_bt_kernel(const unsigned short* __restrict__ A,
                                                      const unsigned short* __restrict__ BT,
                                                      void* __restrict__ Cptr,
                                                      int M, int N, int K) {
  __shared__ unsigned short Alds[128 * 64];
  __shared__ unsigned short Blds[128 * 64];
  const int tid = threadIdx.x;
  const int w = tid >> 6, l = tid & 63;
  const int wr = w >> 1, wc = w & 1;
  const int lg = l >> 4, lr = l & 15;
  const int m0 = blockIdx.y * 128, n0 = blockIdx.x * 128;
  const int lr8 = l >> 3;                 // row within 8-row chunk
  const int lc8 = (l & 7) ^ lr8;          // pre-swizzled source col16 (T2 st-style)

  f32x4 acc[4][4];
#pragma unroll
  for (int i = 0; i < 4; ++i)
#pragma unroll
    for (int j = 0; j < 4; ++j) acc[i][j] = f32x4{0.f, 0.f, 0.f, 0.f};

  for (int k0 = 0; k0 < K; k0 += 64) {
    __syncthreads();
#pragma unroll
    for (int i = 0; i < 4; ++i) {
      const int ch = w * 4 + i;           // 16 chunks of 1024B per tile
      gload_lds16(A + (size_t)(m0 + ch * 8 + lr8) * K + k0 + lc8 * 8, &Alds[ch * 512]);
      gload_lds16(BT + (size_t)(n0 + ch * 8 + lr8) * K + k0 + lc8 * 8, &Blds[ch * 512]);
    }
    __syncthreads();
#pragma unroll
    for (int kc = 0; kc < 2; ++kc) {
      bf16x8 af[4], bfr[4];
#pragma unroll
      for (int mi = 0; mi < 4; ++mi) {
        const int row = wr * 64 + mi * 16 + lr;
        const int c16 = (kc * 4 + lg) ^ (row & 7);
        af[mi] = *(const bf16x8*)(&Alds[row * 64 + c16 * 8]);
      }
#pragma unroll
      for (int nj = 0; nj < 4; ++nj) {
        const int row = wc * 64 + nj * 16 + lr;
        const int c16 = (kc * 4 + lg) ^ (row & 7);
        bfr[nj] = *(const bf16x8*)(&Blds[row * 64 + c16 * 8]);
      }
#pragma unroll
      for (int mi = 0; mi < 4; ++mi)
#pragma unroll
        for (int nj = 0; nj < 4; ++nj)
          acc[mi][nj] = __builtin_amdgcn_mfma_f32_16x16x32_bf16(af[mi], bfr[nj], acc[mi][nj], 0, 0, 0);
    }
  }
#pragma unroll
  for (int mi = 0; mi < 4; ++mi)
#pragma unroll
    for (int nj = 0; nj < 4; ++nj)
#pragma unroll
      for (int j = 0; j < 4; ++j) {
        const int row = m0 + wr * 64 + mi * 16 + lg * 4 + j;  // C/D: row=(lane>>4)*4+j
        const int col = n0 + wc * 64 + nj * 16 + lr;          //      col=lane&15
        if (OUTF32) ((float*)Cptr)[(size_t)row * N + col] = acc[mi][nj][j];
        else ((unsigned short*)Cptr)[(size_t)row * N + col] = f2bf(acc[mi][nj][j]);
      }
}

// ---- fused RoPE-pack (z=0) + V-transpose (z=1) ----
__global__ __launch_bounds__(256) void rope_vtrans_kernel(const unsigned short* __restrict__ QKV,
                                                          unsigned short* __restrict__ Qp,
                                                          unsigned short* __restrict__ Kp,
                                                          unsigned short* __restrict__ Vt) {
  __shared__ unsigned short tile[64][72];
  const int tt = blockIdx.x, bh = blockIdx.y;
  const int b = bh >> 4, h = bh & 15;
  const int tid = threadIdx.x;
  if (blockIdx.z == 0) {
    const int half = tid >> 7;           // 0=q, 1=k
    const int r = (tid >> 1) & 63;
    const int d0 = (tid & 1) * 16;
    const int t = tt * 64 + r;
    const unsigned short* src = QKV + (size_t)(b * T_ + t) * N3_ + half * C_ + h * D_;
    ushortx8 lo0 = *(const ushortx8*)(src + d0);
    ushortx8 lo1 = *(const ushortx8*)(src + d0 + 8);
    ushortx8 hi0 = *(const ushortx8*)(src + d0 + 32);
    ushortx8 hi1 = *(const ushortx8*)(src + d0 + 40);
    ushortx8 olo0, olo1, ohi0, ohi1;
    const float scale = half ? 1.0f : 0.18033688011112042f;
    const float tf = (float)t;
#pragma unroll
    for (int jj = 0; jj < 16; ++jj) {
      const int d = d0 + jj;
      const float invf = exp2f((float)d * -0.41524101186092036f);
      const float ang = tf * invf;
      const float c = cosf(ang), s = sinf(ang);
      const float xl = bf2f(jj < 8 ? lo0[jj] : lo1[jj - 8]);
      const float xh = bf2f(jj < 8 ? hi0[jj] : hi1[jj - 8]);
      const unsigned short rl = f2bf((xl * c - xh * s) * scale);
      const unsigned short rh = f2bf((xh * c + xl * s) * scale);
      if (jj < 8) { olo0[jj] = rl; ohi0[jj] = rh; }
      else        { olo1[jj - 8] = rl; ohi1[jj - 8] = rh; }
    }
    unsigned short* dst = (half ? Kp : Qp) + ((size_t)bh * T_ + t) * D_;
    *(ushortx8*)(dst + d0) = olo0;
    *(ushortx8*)(dst + d0 + 8) = olo1;
    *(ushortx8*)(dst + d0 + 32) = ohi0;
    *(ushortx8*)(dst + d0 + 40) = ohi1;
  } else {
    {
      const int r = tid >> 2, seg = tid & 3;
      const unsigned short* src = QKV + (size_t)(b * T_ + tt * 64 + r) * N3_ + 2 * C_ + h * D_ + seg * 16;
      *(ushortx8*)(&tile[r][seg * 16]) = *(const ushortx8*)(src);
      *(ushortx8*)(&tile[r][seg * 16 + 8]) = *(const ushortx8*)(src + 8);
    }
    __syncthreads();
    {
      const int d = tid >> 2, ts = tid & 3;
      ushortx8 o0, o1;
#pragma unroll
      for (int i = 0; i < 8; ++i) { o0[i] = tile[ts * 16 + i][d]; o1[i] = tile[ts * 16 + 8 + i][d]; }
      unsigned short* dst = Vt + ((size_t)bh * D_ + d) * T_ + tt * 64 + ts * 16;
      *(ushortx8*)(dst) = o0;
      *(ushortx8*)(dst + 8) = o1;
    }
  }
}

// -------- causal flash attention v10: KVBLK=128, joint softmax, dbuf staging --------
// Block g covers strips {4g..4g+3} (wave w <-> strip 4g+w, q0 = 128g+32w).
// nt = g+1 iterations of 128 kv each; all 4 waves active every iteration.
// Per iteration: {barrier(prior reads of nxt-buf retired) -> issue tile t+1 ->
// vmcnt(8)(own t loads) -> barrier(all t loads) -> 16 QK MFMA (4 indep accs) ->
// joint 128-wide softmax (one max tree, one exp2 batch, defer-max) -> 8 P-frags
// -> 16 PV MFMA}. Dispatch pairing g/(15-g) -> 17 iters per CU, constant.
__global__ __launch_bounds__(256, 2) void attn10_kernel(const unsigned short* __restrict__ Qp,
                                                        const unsigned short* __restrict__ Kp,
                                                        const unsigned short* __restrict__ Vt,
                                                        unsigned short* __restrict__ Ob) {
  __shared__ unsigned short Klds[2][128 * 64];   // [buf][kv][d]  16KB each
  __shared__ unsigned short Vlds[2][64 * 128];   // [buf][d][kv]  16KB each  -> 64KB
  const int tid = threadIdx.x, w = tid >> 6, l = tid & 63;
  const int lq = l & 31, hi = l >> 5;
  const int swz = lq & 7;
  const int bid = blockIdx.x;
  const int bh = bid & 31;                      // same head -> same XCD (bid%8)
  const int j = bid >> 5;                       // 0..15
  const int g = (j < 8) ? (15 - j) : (j - 8);   // round1: g=15..8; round2: g=0..7
  const int q0 = (4 * g + w) * 32;              // this wave's 32 q-rows
  const int nt = g + 1;                         // 128-kv tiles
  const size_t koff = (size_t)bh * T_ * D_;
  const unsigned short* Kb = Kp + koff;
  const unsigned short* Vb = Vt + (size_t)bh * D_ * T_;

  const int lr8 = l >> 3;               // K staging: row within 8-row chunk
  const int lc8 = (l & 7) ^ lr8;        // pre-swizzled source 16B slot (K)
  const int vrl = l >> 4;               // V staging: row within 4-row chunk
  const int vsl = l & 15;               // V dest 16B slot

  // Q B-frags: lane holds Q[q0+lq][ds*16 + hi*8 + ..]
  bf16x8 qf[4];
  {
    const unsigned short* qp = Qp + koff + (size_t)(q0 + lq) * D_ + hi * 8;
#pragma unroll
    for (int ds = 0; ds < 4; ++ds) qf[ds] = *(const bf16x8*)(qp + ds * 16);
  }
  f32x16 o0, o1;
#pragma unroll
  for (int r = 0; r < 16; ++r) { o0[r] = 0.f; o1[r] = 0.f; }
  float m = -3.0e38f, lden = 0.f;

  // stage one 128-kv tile (K: 16 chunks of 8rows x 64d; V: 16 chunks of 4rows x 128kv);
  // wave w stages K chunks 4w..4w+3 and V chunks 4w..4w+3 (8 loads)
  auto stage = [&](int buf, int kv0s) {
#pragma unroll
    for (int i = 0; i < 4; ++i) {
      const int c = w * 4 + i;
      gload_lds16(Kb + (size_t)(kv0s + c * 8 + lr8) * D_ + lc8 * 8, &Klds[buf][c * 512]);
    }
#pragma unroll
    for (int i = 0; i < 4; ++i) {
      const int c = w * 4 + i;
      const int vr = c * 4 + vrl;                 // global d-row (0..63)
      const int vs = vsl ^ (vr & 7);              // pre-swizzled source 16B slot
      gload_lds16(Vb + (size_t)vr * T_ + kv0s + vs * 8, &Vlds[buf][c * 512]);
    }
  };
  // pack f32x16 p (already exp'd) -> two bf16x8 B-frags (T12)
  auto pack2 = [&](const f32x16& p, bf16x8& fa, bf16x8& fb) {
    unsigned W0 = cvtpk_bf16(p[0], p[1]), W1 = cvtpk_bf16(p[2], p[3]);
    unsigned W2 = cvtpk_bf16(p[4], p[5]), W3 = cvtpk_bf16(p[6], p[7]);
    uintx2 Aa = __builtin_amdgcn_permlane32_swap(W0, W2, false, false);
    uintx2 Ab = __builtin_amdgcn_permlane32_swap(W1, W3, false, false);
    union { unsigned u[4]; bf16x8 v; } t1 = {{Aa.x, Ab.x, Aa.y, Ab.y}};
    fa = t1.v;
    W0 = cvtpk_bf16(p[8], p[9]);   W1 = cvtpk_bf16(p[10], p[11]);
    W2 = cvtpk_bf16(p[12], p[13]); W3 = cvtpk_bf16(p[14], p[15]);
    Aa = __builtin_amdgcn_permlane32_swap(W0, W2, false, false);
    Ab = __builtin_amdgcn_permlane32_swap(W1, W3, false, false);
    union { unsigned u[4]; bf16x8 v; } t2 = {{Aa.x, Ab.x, Aa.y, Ab.y}};
    fb = t2.v;
  };

  stage(0, 0);   // prologue: tile 0 -> buf 0

  for (int kt = 0; kt < nt; ++kt) {
    const int cur = kt & 1, nxt = cur ^ 1;
    __builtin_amdgcn_s_barrier();            // all reads of buf[nxt] (iter kt-1) retired
    const int ktn = (kt + 1 < nt) ? kt + 1 : kt;
    stage(nxt, ktn * 128);                   // issue tile kt+1 (clamped re-stage on last)
    asm volatile("s_waitcnt vmcnt(8)" ::: "memory");   // own tile-kt loads landed
    __builtin_amdgcn_s_barrier();            // everyone's tile-kt loads landed
    __builtin_amdgcn_sched_barrier(0);

    const unsigned short* KL = &Klds[cur][0];
    const unsigned short* VL = &Vlds[cur][0];
    const int kv0 = kt * 128;
    // S^T = K . Q^T over d=64, four 32-kv groups (independent MFMA chains)
    f32x16 a0, a1, a2, a3;
#pragma unroll
    for (int r = 0; r < 16; ++r) { a0[r] = 0.f; a1[r] = 0.f; a2[r] = 0.f; a3[r] = 0.f; }
    __builtin_amdgcn_s_setprio(1);
#pragma unroll
    for (int ds = 0; ds < 4; ++ds) {
      const int slot = ((ds * 2 + hi) ^ swz) * 8;
      const bf16x8 k0f = *(const bf16x8*)(&KL[(lq) * 64 + slot]);
      const bf16x8 k1f = *(const bf16x8*)(&KL[(32 + lq) * 64 + slot]);
      const bf16x8 k2f = *(const bf16x8*)(&KL[(64 + lq) * 64 + slot]);
      const bf16x8 k3f = *(const bf16x8*)(&KL[(96 + lq) * 64 + slot]);
      a0 = __builtin_amdgcn_mfma_f32_32x32x16_bf16(k0f, qf[ds], a0, 0, 0, 0);
      a1 = __builtin_amdgcn_mfma_f32_32x32x16_bf16(k1f, qf[ds], a1, 0, 0, 0);
      a2 = __builtin_amdgcn_mfma_f32_32x32x16_bf16(k2f, qf[ds], a2, 0, 0, 0);
      a3 = __builtin_amdgcn_mfma_f32_32x32x16_bf16(k3f, qf[ds], a3, 0, 0, 0);
    }
    __builtin_amdgcn_s_setprio(0);
    if (kv0 + 127 > q0) {    // diagonal iteration (kt == g): mask kv_global > q_global
      const int thr = q0 + lq - kv0;
#pragma unroll
      for (int r = 0; r < 16; ++r) {
        const int kvloc = (r & 3) + 8 * (r >> 2) + 4 * hi;
        if (kvloc > thr)      a0[r] = -3.0e38f;
        if (kvloc > thr - 32) a1[r] = -3.0e38f;
        if (kvloc > thr - 64) a2[r] = -3.0e38f;
        if (kvloc > thr - 96) a3[r] = -3.0e38f;
      }
    }
    // joint max over 128 kv: in-lane tree + cross-half permlane swap
    float mx[8];
#pragma unroll
    for (int i = 0; i < 8; ++i)
      mx[i] = fmaxf(fmaxf(fmaxf(a0[i], a0[i + 8]), fmaxf(a1[i], a1[i + 8])),
                    fmaxf(fmaxf(a2[i], a2[i + 8]), fmaxf(a3[i], a3[i + 8])));
#pragma unroll
    for (int i = 0; i < 4; ++i) mx[i] = fmaxf(mx[i], mx[i + 4]);
    const float mloc = fmaxf(fmaxf(mx[0], mx[1]), fmaxf(mx[2], mx[3]));
    const uintx2 mp = __builtin_amdgcn_permlane32_swap(__float_as_uint(mloc), __float_as_uint(mloc), false, false);
    const float pm = fmaxf(__uint_as_float(mp.x), __uint_as_float(mp.y));
    // defer-max (T13): rescale only when max grew by > 8
    const bool grow = pm > m + 8.0f;
    if (__any(grow)) {
      const float mn = grow ? pm : m;
      const float alpha = __builtin_amdgcn_exp2f(m - mn);
      m = mn;
      lden *= alpha;
#pragma unroll
      for (int r = 0; r < 16; ++r) { o0[r] *= alpha; o1[r] *= alpha; }
    }
    // P = exp2(S - m) in place (64 exp2, one batch)
#pragma unroll
    for (int r = 0; r < 16; ++r) {
      a0[r] = __builtin_amdgcn_exp2f(a0[r] - m);
      a1[r] = __builtin_amdgcn_exp2f(a1[r] - m);
      a2[r] = __builtin_amdgcn_exp2f(a2[r] - m);
      a3[r] = __builtin_amdgcn_exp2f(a3[r] - m);
    }
    // P -> 8 B-frags (T12)
    bf16x8 f0, f1, f2, f3, f4, f5, f6, f7;
    pack2(a0, f0, f1); pack2(a1, f2, f3); pack2(a2, f4, f5); pack2(a3, f6, f7);
    // O^T += V^T . P^T (16 MFMAs; kv slices j*16 -> frag j)
    __builtin_amdgcn_s_setprio(1);
#pragma unroll
    for (int dt = 0; dt < 2; ++dt) {
      const int rowb = (dt * 32 + lq) * 128;
      const bf16x8 v0 = *(const bf16x8*)(&VL[rowb + ((0 * 2 + hi) ^ swz) * 8]);
      const bf16x8 v1 = *(const bf16x8*)(&VL[rowb + ((1 * 2 + hi) ^ swz) * 8]);
      const bf16x8 v2 = *(const bf16x8*)(&VL[rowb + ((2 * 2 + hi) ^ swz) * 8]);
      const bf16x8 v3 = *(const bf16x8*)(&VL[rowb + ((3 * 2 + hi) ^ swz) * 8]);
      const bf16x8 v4 = *(const bf16x8*)(&VL[rowb + ((4 * 2 + hi) ^ swz) * 8]);
      const bf16x8 v5 = *(const bf16x8*)(&VL[rowb + ((5 * 2 + hi) ^ swz) * 8]);
      const bf16x8 v6 = *(const bf16x8*)(&VL[rowb + ((6 * 2 + hi) ^ swz) * 8]);
      const bf16x8 v7 = *(const bf16x8*)(&VL[rowb + ((7 * 2 + hi) ^ swz) * 8]);
      if (dt == 0) {
        o0 = __builtin_amdgcn_mfma_f32_32x32x16_bf16(v0, f0, o0, 0, 0, 0);
        o0 = __builtin_amdgcn_mfma_f32_32x32x16_bf16(v1, f1, o0, 0, 0, 0);
        o0 = __builtin_amdgcn_mfma_f32_32x32x16_bf16(v2, f2, o0, 0, 0, 0);
        o0 = __builtin_amdgcn_mfma_f32_32x32x16_bf16(v3, f3, o0, 0, 0, 0);
        o0 = __builtin_amdgcn_mfma_f32_32x32x16_bf16(v4, f4, o0, 0, 0, 0);
        o0 = __builtin_amdgcn_mfma_f32_32x32x16_bf16(v5, f5, o0, 0, 0, 0);
        o0 = __builtin_amdgcn_mfma_f32_32x32x16_bf16(v6, f6, o0, 0, 0, 0);
        o0 = __builtin_amdgcn_mfma_f32_32x32x16_bf16(v7, f7, o0, 0, 0, 0);
      } else {
        o1 = __builtin_amdgcn_mfma_f32_32x32x16_bf16(v0, f0, o1, 0, 0, 0);
        o1 = __builtin_amdgcn_mfma_f32_32x32x16_bf16(v1, f1, o1, 0, 0, 0);
        o1 = __builtin_amdgcn_mfma_f32_32x32x16_bf16(v2, f2, o1, 0, 0, 0);
        o1 = __builtin_amdgcn_mfma_f32_32x32x16_bf16(v3, f3, o1, 0, 0, 0);
        o1 = __builtin_amdgcn_mfma_f32_32x32x16_bf16(v4, f4, o1, 0, 0, 0);
        o1 = __builtin_amdgcn_mfma_f32_32x32x16_bf16(v5, f5, o1, 0, 0, 0);
        o1 = __builtin_amdgcn_mfma_f32_32x32x16_bf16(v6, f6, o1, 0, 0, 0);
        o1 = __builtin_amdgcn_mfma_f32_32x32x16_bf16(v7, f7, o1, 0, 0, 0);
      }
    }
    __builtin_amdgcn_s_setprio(0);
    // lsum over 128 (overlaps PV on VALU pipe)
    float sm[8];
#pragma unroll
    for (int i = 0; i < 8; ++i)
      sm[i] = ((a0[i] + a0[i + 8]) + (a1[i] + a1[i + 8])) +
              ((a2[i] + a2[i + 8]) + (a3[i] + a3[i + 8]));
#pragma unroll
    for (int i = 0; i < 4; ++i) sm[i] = sm[i] + sm[i + 4];
    const float sloc = (sm[0] + sm[1]) + (sm[2] + sm[3]);
    const uintx2 sp = __builtin_amdgcn_permlane32_swap(__float_as_uint(sloc), __float_as_uint(sloc), false, false);
    lden += __uint_as_float(sp.x) + __uint_as_float(sp.y);
  }
  asm volatile("s_waitcnt vmcnt(0)" ::: "memory");   // drain trailing prefetch

  // epilogue: lane holds q=q0+lq, d = dt*32 + rq*8 + 4*hi + i
  const float rl = __builtin_amdgcn_rcpf(lden);
  const int b = bh >> 4, hh = bh & 15;
  unsigned short* orow = Ob + (size_t)(b * T_ + q0 + lq) * C_ + hh * D_ + 4 * hi;
#pragma unroll
  for (int rq = 0; rq < 4; ++rq) {
    ushortx4 ov0, ov1;
#pragma unroll
    for (int i = 0; i < 4; ++i) {
      ov0[i] = f2bf(o0[rq * 4 + i] * rl);
      ov1[i] = f2bf(o1[rq * 4 + i] * rl);
    }
    *(ushortx4*)(orow + rq * 8) = ov0;
    *(ushortx4*)(orow + 32 + rq * 8) = ov1;
  }
}

// ---------------- launch ----------------
extern "C" void kernel_launch(void* const* d_in, const int* in_sizes, int n_in,
                              void* d_out, int out_size, void* d_ws, size_t ws_size,
                              hipStream_t stream) {
  const float* x = (const float*)d_in[0];
  const float* Wqkv = (const float*)d_in[1];
  const float* Wout = (const float*)d_in[2];
  float* out = (float*)d_out;
  char* ws = (char*)d_ws;
  // workspace layout (72 MiB total)
  unsigned short* Xb    = (unsigned short*)(ws);                  //  8 MiB [4096][1024]
  unsigned short* WqkvT = (unsigned short*)(ws + (8ull << 20));   //  6 MiB [3072][1024]
  unsigned short* WoutT = (unsigned short*)(ws + (14ull << 20));  //  2 MiB [1024][1024]
  unsigned short* QKVb  = (unsigned short*)(ws + (16ull << 20));  // 24 MiB [4096][3072]
  unsigned short* Qp    = (unsigned short*)(ws + (40ull << 20));  //  8 MiB [32][2048][64]
  unsigned short* Kp    = (unsigned short*)(ws + (48ull << 20));  //  8 MiB
  unsigned short* Vt    = (unsigned short*)(ws + (56ull << 20));  //  8 MiB [32][64][2048]
  unsigned short* Ob    = (unsigned short*)(ws + (64ull << 20));  //  8 MiB [4096][1024]

  prep_kernel<<<8192, 256, 0, stream>>>(x, Xb, Wqkv, WqkvT, Wout, WoutT);
  gemm_bt_kernel<0><<<dim3(N3_ / 128, (B_ * T_) / 128), 256, 0, stream>>>(
      Xb, WqkvT, QKVb, B_ * T_, N3_, C_);
  rope_vtrans_kernel<<<dim3(T_ / 64, B_ * H_, 2), 256, 0, stream>>>(QKVb, Qp, Kp, Vt);
  attn10_kernel<<<512, 256, 0, stream>>>(Qp, Kp, Vt, Ob);
  gemm_bt_kernel<1><<<dim3(C_ / 128, (B_ * T_) / 128), 256, 0, stream>>>(
      Ob, WoutT, out, B_ * T_, C_, C_);
}